// Round 5
// baseline (966.687 us; speedup 1.0000x reference)
//
#include <hip/hip_runtime.h>

#define NN 50000
#define NP 50048
#define NE 800000
#define CH 512
#define NB 196        // ceil(50000/256) scan blocks
#define PB_CONV 12512 // NP*CH/8/256
#define PB_TRANS 2048 // 2 * CH*CH/256
#define PB_DEG 782    // ceil(NE/4/256)
#define SMB 49        // softmax partial blocks (49*1024 >= 50000)
#define NGRP 12500    // 50000/4 node groups for chunked agg

typedef __bf16 bf16x8 __attribute__((ext_vector_type(8)));
typedef float f32x4 __attribute__((ext_vector_type(4)));
typedef unsigned short u16x8 __attribute__((ext_vector_type(8)));

static __device__ __forceinline__ unsigned short f2b(float f){
  unsigned u = __builtin_bit_cast(unsigned, f);
  u = (u + 0x7fffu + ((u >> 16) & 1u)) >> 16;   // RNE f32 -> bf16
  return (unsigned short)u;
}
static __device__ __forceinline__ float b2f(unsigned short h){
  unsigned u = ((unsigned)h) << 16;
  return __builtin_bit_cast(float, u);
}
static __device__ __forceinline__ float rdlane_f(float v, int l){
  return __builtin_bit_cast(float, __builtin_amdgcn_readlane(__builtin_bit_cast(int, v), l));
}

// ---- merged prep: x->bf16 convert | W1/W2 transpose->bf16 | degree histogram ----
__global__ void k_prep(const float* __restrict__ x, unsigned short* __restrict__ xb,
                       const float* __restrict__ W1, const float* __restrict__ W2,
                       unsigned short* __restrict__ W1t, unsigned short* __restrict__ W2t,
                       const int* __restrict__ ei, int* __restrict__ deg){
  const int b = blockIdx.x, t = threadIdx.x;
  if (b < PB_CONV){
    int base = (b * 256 + t) * 8;
    int row = base >> 9;
    u16x8 o;
    if (row < NN){
      const float4* p = (const float4*)(x + base);
      float4 a = p[0], c = p[1];
      o[0]=f2b(a.x); o[1]=f2b(a.y); o[2]=f2b(a.z); o[3]=f2b(a.w);
      o[4]=f2b(c.x); o[5]=f2b(c.y); o[6]=f2b(c.z); o[7]=f2b(c.w);
    } else {
      #pragma unroll
      for (int k=0;k<8;k++) o[k]=0;
    }
    *(u16x8*)(xb + base) = o;
  } else if (b < PB_CONV + PB_TRANS){
    int bb = b - PB_CONV;
    const float* W = (bb < 1024) ? W1 : W2;
    unsigned short* Wt = (bb < 1024) ? W1t : W2t;
    int idx = (bb & 1023) * 256 + t;
    int n = idx >> 9, k = idx & (CH - 1);
    Wt[n * CH + k] = f2b(W[k * CH + n]);
  } else {
    int e4 = ((b - PB_CONV - PB_TRANS) * 256 + t) * 4;
    if (e4 < NE){
      int4 d = *(const int4*)(ei + NE + e4);
      atomicAdd(&deg[d.x], 1); atomicAdd(&deg[d.y], 1);
      atomicAdd(&deg[d.z], 1); atomicAdd(&deg[d.w], 1);
    }
  }
}

// ---- hierarchical scan: block sums -> scan -> scatter ----
__global__ void k_blocksum(const int* __restrict__ deg, int* __restrict__ bsum){
  __shared__ int sh[4];
  const int t = threadIdx.x;
  int i = blockIdx.x * 256 + t;
  int v = (i < NN) ? deg[i] : 0;
  #pragma unroll
  for (int off = 32; off > 0; off >>= 1) v += __shfl_down(v, off, 64);
  if ((t & 63) == 0) sh[t >> 6] = v;
  __syncthreads();
  if (t == 0) bsum[blockIdx.x] = sh[0] + sh[1] + sh[2] + sh[3];
}

__global__ void k_scanoff(const int* __restrict__ bsum, int* __restrict__ boff,
                          int* __restrict__ row_ptr){
  __shared__ int sh[256];
  const int t = threadIdx.x;
  int v = (t < NB) ? bsum[t] : 0;
  sh[t] = v; __syncthreads();
  for (int d = 1; d < 256; d <<= 1){
    int add = (t >= d) ? sh[t - d] : 0;
    __syncthreads();
    sh[t] += add;
    __syncthreads();
  }
  if (t < NB) boff[t] = sh[t] - v;
  if (t == 255) row_ptr[NN] = sh[255];
}

__global__ void k_scatter(const int* __restrict__ deg, const int* __restrict__ boff,
                          int* __restrict__ row_ptr, int* __restrict__ cursor,
                          float* __restrict__ dinv){
  __shared__ int sh[256];
  const int t = threadIdx.x;
  int i = blockIdx.x * 256 + t;
  int d = (i < NN) ? deg[i] : 0;
  sh[t] = d; __syncthreads();
  for (int dd = 1; dd < 256; dd <<= 1){
    int add = (t >= dd) ? sh[t - dd] : 0;
    __syncthreads();
    sh[t] += add;
    __syncthreads();
  }
  if (i < NN){
    int ex = sh[t] - d + boff[blockIdx.x];
    row_ptr[i] = ex; cursor[i] = ex;
    dinv[i] = rsqrtf((float)d + 1.0f);   // +1 self-loop
  }
}

// ---- bucket edges by dst (2 edges/thread) ----
__global__ void k_bucket(const int* __restrict__ ei, int* __restrict__ cursor,
                         int* __restrict__ csr_src){
  int e2 = (blockIdx.x * blockDim.x + threadIdx.x) * 2;
  if (e2 >= NE) return;
  int2 src = *(const int2*)(ei + e2);
  int2 dst = *(const int2*)(ei + NE + e2);
  csr_src[atomicAdd(&cursor[dst.x], 1)] = src.x;
  csr_src[atomicAdd(&cursor[dst.y], 1)] = src.y;
}

// ---- bf16 MFMA GEMM: C[M,512] = A @ Bt^T, 128x256 block tile ----
__launch_bounds__(256, 2)
__global__ void k_gemm(const unsigned short* __restrict__ A,
                       const unsigned short* __restrict__ Bt,
                       unsigned short* __restrict__ C){
  __shared__ __align__(16) unsigned short As[128 * 32];   // 8 KB
  __shared__ __align__(16) unsigned short Bs[256 * 32];   // 16 KB
  const int t = threadIdx.x;
  const int wave = t >> 6, lane = t & 63;
  const int quad = lane >> 4, l15 = lane & 15;
  const int mw = (wave & 1) * 64;
  const int nw = (wave >> 1) * 128;
  const int rowBase = blockIdx.x * 128;
  const int nBase = blockIdx.y * 256;

  const int lr = lane >> 2;
  const int lc = (lane & 3) * 8;
  const unsigned short* Ag0 = A  + (size_t)(rowBase + wave * 32 + lr) * CH + lc;
  const unsigned short* Bg0 = Bt + (size_t)(nBase + wave * 64 + lr) * CH + lc;
  unsigned short* Al0 = As + wave * 2 * 512;
  unsigned short* Bl0 = Bs + wave * 4 * 512;

  f32x4 acc[4][8];
  #pragma unroll
  for (int i=0;i<4;i++)
    #pragma unroll
    for (int j=0;j<8;j++) acc[i][j] = 0;

  for (int kb = 0; kb < CH; kb += 32){
    #pragma unroll
    for (int q=0;q<2;q++)
      __builtin_amdgcn_global_load_lds(
        (const __attribute__((address_space(1))) void*)(Ag0 + (size_t)q*16*CH + kb),
        (__attribute__((address_space(3))) void*)(Al0 + q*512), 16, 0, 0);
    #pragma unroll
    for (int q=0;q<4;q++)
      __builtin_amdgcn_global_load_lds(
        (const __attribute__((address_space(1))) void*)(Bg0 + (size_t)q*16*CH + kb),
        (__attribute__((address_space(3))) void*)(Bl0 + q*512), 16, 0, 0);
    __syncthreads();

    bf16x8 af[4], bfr[8];
    #pragma unroll
    for (int i=0;i<4;i++)
      af[i] = __builtin_bit_cast(bf16x8,
              *(const u16x8*)&As[(mw + i*16 + l15) * 32 + quad * 8]);
    #pragma unroll
    for (int j=0;j<8;j++)
      bfr[j] = __builtin_bit_cast(bf16x8,
              *(const u16x8*)&Bs[(nw + j*16 + l15) * 32 + quad * 8]);
    #pragma unroll
    for (int i=0;i<4;i++)
      #pragma unroll
      for (int j=0;j<8;j++)
        acc[i][j] = __builtin_amdgcn_mfma_f32_16x16x32_bf16(af[i], bfr[j], acc[i][j], 0, 0, 0);
    __syncthreads();
  }

  #pragma unroll
  for (int i=0;i<4;i++){
    #pragma unroll
    for (int j=0;j<8;j++){
      int r0 = rowBase + mw + i*16 + quad*4;
      int c  = nBase + nw + j*16 + l15;
      #pragma unroll
      for (int r=0;r<4;r++)
        C[(size_t)(r0 + r) * CH + c] = f2b(acc[i][j][r]);
    }
  }
}

// ---- channel-chunked aggregation, XCD-pinned L2-resident chunks ----
// chunk = 32 channels (3.2 MB table slice, fits a 4 MB XCD L2).
// grid: x in [0,8) = XCD slot; y = pair*NGRP + grp; chunk = x + 8*pair.
// wave handles (node, chunk): 4 lanes/edge (16B = 8ch each), 16 edges in flight,
// butterfly-reduce over edge-groups (lane bits 2..5).
template<bool HEAD>
__launch_bounds__(256)
__global__ void k_aggc(const unsigned short* __restrict__ h, const int* __restrict__ row_ptr,
                       const int* __restrict__ csr_src, const float* __restrict__ dinv,
                       const float* __restrict__ bias, unsigned short* __restrict__ out,
                       const float* __restrict__ Wo, float* __restrict__ logits){
  const int pair = blockIdx.y / NGRP;
  const int grp  = blockIdx.y - pair * NGRP;
  const int chunk = blockIdx.x + 8 * pair;       // 0..15
  const int wave = threadIdx.x >> 6;
  const int node = grp * 4 + wave;
  const int lane = threadIdx.x & 63;
  const int eg = lane >> 2;                      // edge slot 0..15
  const int sub = lane & 3;                      // 16B piece within 64B chunk row
  const int cbase = chunk * 32 + sub * 8;

  const int rp = row_ptr[node], re = row_ptr[node + 1];
  float acc[8];
  #pragma unroll
  for (int k=0;k<8;k++) acc[k] = 0.f;

  for (int base = rp; base < re; base += 16){
    int idx = base + eg;
    int s = node; float w = 0.f;
    if (idx < re){ s = csr_src[idx]; w = dinv[s]; }
    u16x8 hv = *(const u16x8*)(h + (size_t)s * CH + cbase);
    #pragma unroll
    for (int k=0;k<8;k++) acc[k] += w * b2f(hv[k]);
  }
  // reduce across the 16 edge-groups (lane bits 2..5)
  #pragma unroll
  for (int m = 4; m <= 32; m <<= 1)
    #pragma unroll
    for (int k=0;k<8;k++) acc[k] += __shfl_xor(acc[k], m, 64);

  const float di = dinv[node];
  u16x8 hs = *(const u16x8*)(h + (size_t)node * CH + cbase);
  float4 bv0 = *(const float4*)(bias + cbase);
  float4 bv1 = *(const float4*)(bias + cbase + 4);
  float bb[8] = {bv0.x,bv0.y,bv0.z,bv0.w,bv1.x,bv1.y,bv1.z,bv1.w};

  if (HEAD){
    float4 w0 = *(const float4*)(Wo + cbase);
    float4 w1 = *(const float4*)(Wo + cbase + 4);
    float wv[8] = {w0.x,w0.y,w0.z,w0.w,w1.x,w1.y,w1.z,w1.w};
    float v = 0.f;
    #pragma unroll
    for (int k=0;k<8;k++){
      float r = fmaxf(di * acc[k] + di * di * b2f(hs[k]) + bb[k], 0.f);
      v += r * wv[k];
    }
    v += __shfl_xor(v, 1, 64);
    v += __shfl_xor(v, 2, 64);
    if (lane == 0) atomicAdd(&logits[node], v);   // bo dropped: softmax shift-invariant
  } else {
    u16x8 o;
    #pragma unroll
    for (int k=0;k<8;k++){
      float r = fmaxf(di * acc[k] + di * di * b2f(hs[k]) + bb[k], 0.f);
      o[k] = f2b(r);
    }
    if (eg == 0)
      *(u16x8*)(out + (size_t)node * CH + cbase) = o;
  }
}

// ---- softmax: 49-block partial (m_b, s_b) + 64-lane online combine ----
__global__ void k_smpart(const float* __restrict__ logits, float* __restrict__ pm,
                         float* __restrict__ ps){
  __shared__ float shm[16], shs[16];
  const int t = threadIdx.x;
  const int i = blockIdx.x * 1024 + t;
  float v = (i < NN) ? logits[i] : -3.4e38f;
  float m = v;
  #pragma unroll
  for (int off = 32; off > 0; off >>= 1) m = fmaxf(m, __shfl_down(m, off, 64));
  if ((t & 63) == 0) shm[t >> 6] = m;
  __syncthreads();
  if (t < 64){
    float mm = (t < 16) ? shm[t] : -3.4e38f;
    #pragma unroll
    for (int off = 8; off > 0; off >>= 1) mm = fmaxf(mm, __shfl_down(mm, off, 64));
    if (t == 0) shm[0] = mm;
  }
  __syncthreads();
  const float bm = shm[0];
  float s = (i < NN) ? expf(v - bm) : 0.f;
  #pragma unroll
  for (int off = 32; off > 0; off >>= 1) s += __shfl_down(s, off, 64);
  if ((t & 63) == 0) shs[t >> 6] = s;
  __syncthreads();
  if (t < 64){
    float sss = (t < 16) ? shs[t] : 0.f;
    #pragma unroll
    for (int off = 8; off > 0; off >>= 1) sss += __shfl_down(sss, off, 64);
    if (t == 0){ pm[blockIdx.x] = bm; ps[blockIdx.x] = sss; }
  }
}

__global__ void k_smfinal(const float* __restrict__ pm, const float* __restrict__ ps,
                          float* __restrict__ scr){
  const int t = threadIdx.x;   // 64 threads
  float m = (t < SMB) ? pm[t] : -3.4e38f;
  float M = m;
  #pragma unroll
  for (int off = 32; off > 0; off >>= 1) M = fmaxf(M, __shfl_down(M, off, 64));
  M = rdlane_f(M, 0);
  float s = (t < SMB) ? ps[t] * expf(m - M) : 0.f;
  #pragma unroll
  for (int off = 32; off > 0; off >>= 1) s += __shfl_down(s, off, 64);
  if (t == 0){ scr[0] = M; scr[1] = s; }
}

__global__ void k_smwrite(const float* __restrict__ logits, const float* __restrict__ scr,
                          float* __restrict__ out){
  int i = blockIdx.x * blockDim.x + threadIdx.x;
  if (i >= NN) return;
  out[i] = expf(logits[i] - scr[0]) / scr[1];
}

extern "C" void kernel_launch(void* const* d_in, const int* in_sizes, int n_in,
                              void* d_out, int out_size, void* d_ws, size_t ws_size,
                              hipStream_t stream){
  const float* x  = (const float*)d_in[0];
  const int*   ei = (const int*)d_in[1];
  const float* W1 = (const float*)d_in[2];
  const float* b1 = (const float*)d_in[3];
  const float* W2 = (const float*)d_in[4];
  const float* b2 = (const float*)d_in[5];
  const float* Wo = (const float*)d_in[6];
  float* out = (float*)d_out;

  char* ws = (char*)d_ws;
  size_t off = 0;
  auto alloc = [&](size_t bytes) -> void* {
    void* p = ws + off;
    off = (off + bytes + 255) & ~(size_t)255;
    return p;
  };
  unsigned short* B0  = (unsigned short*)alloc((size_t)NP * CH * 2);
  unsigned short* B1  = (unsigned short*)alloc((size_t)NP * CH * 2);
  unsigned short* W1t = (unsigned short*)alloc((size_t)CH * CH * 2);
  unsigned short* W2t = (unsigned short*)alloc((size_t)CH * CH * 2);
  int*   deg     = (int*)alloc((size_t)NN * 4);
  float* dinv    = (float*)alloc((size_t)NN * 4);
  int*   row_ptr = (int*)alloc((size_t)(NN + 1) * 4);
  int*   cursor  = (int*)alloc((size_t)NN * 4);
  int*   csr     = (int*)alloc((size_t)NE * 4);
  float* logits  = (float*)alloc((size_t)NN * 4);
  int*   bsum    = (int*)alloc((size_t)NB * 4);
  int*   boff    = (int*)alloc((size_t)NB * 4);
  float* pm      = (float*)alloc((size_t)SMB * 4);
  float* ps      = (float*)alloc((size_t)SMB * 4);
  float* scr     = (float*)alloc(256);

  hipMemsetAsync(deg, 0, (size_t)NN * 4, stream);
  hipMemsetAsync(logits, 0, (size_t)NN * 4, stream);
  k_prep<<<PB_CONV + PB_TRANS + PB_DEG, 256, 0, stream>>>(x, B0, W1, W2, W1t, W2t, ei, deg);
  k_blocksum<<<NB, 256, 0, stream>>>(deg, bsum);
  k_scanoff<<<1, 256, 0, stream>>>(bsum, boff, row_ptr);
  k_scatter<<<NB, 256, 0, stream>>>(deg, boff, row_ptr, cursor, dinv);
  k_bucket<<<(NE / 2 + 255) / 256, 256, 0, stream>>>(ei, cursor, csr);

  k_gemm<<<dim3(NP / 128, CH / 256), 256, 0, stream>>>(B0, W1t, B1);
  k_aggc<false><<<dim3(8, 2 * NGRP), 256, 0, stream>>>(B1, row_ptr, csr, dinv, b1, B0,
                                                       Wo, logits);
  k_gemm<<<dim3(NP / 128, CH / 256), 256, 0, stream>>>(B0, W2t, B1);
  k_aggc<true><<<dim3(8, 2 * NGRP), 256, 0, stream>>>(B1, row_ptr, csr, dinv, b2, B0,
                                                      Wo, logits);

  k_smpart<<<SMB, 1024, 0, stream>>>(logits, pm, ps);
  k_smfinal<<<1, 64, 0, stream>>>(pm, ps, scr);
  k_smwrite<<<(NN + 255) / 256, 256, 0, stream>>>(logits, scr, out);
}

// Round 6
// 589.659 us; speedup vs baseline: 1.6394x; 1.6394x over previous
//
#include <hip/hip_runtime.h>

#define NN 50000
#define NP 50048
#define NE 800000
#define CH 512
#define NB 196        // ceil(50000/256) scan blocks
#define PB_CONV 12512 // NP*CH/8/256
#define PB_TRANS 2048 // 2 * CH*CH/256
#define PB_DEG 782    // ceil(NE/4/256)
#define SMB 49        // softmax partial blocks (49*1024 >= 50000)

typedef __bf16 bf16x8 __attribute__((ext_vector_type(8)));
typedef float f32x4 __attribute__((ext_vector_type(4)));
typedef unsigned short u16x8 __attribute__((ext_vector_type(8)));

static __device__ __forceinline__ unsigned short f2b(float f){
  unsigned u = __builtin_bit_cast(unsigned, f);
  u = (u + 0x7fffu + ((u >> 16) & 1u)) >> 16;   // RNE f32 -> bf16
  return (unsigned short)u;
}
static __device__ __forceinline__ float b2f(unsigned short h){
  unsigned u = ((unsigned)h) << 16;
  return __builtin_bit_cast(float, u);
}
static __device__ __forceinline__ float rdlane_f(float v, int l){
  return __builtin_bit_cast(float, __builtin_amdgcn_readlane(__builtin_bit_cast(int, v), l));
}

// ---- merged prep: x->bf16 convert | W1/W2 transpose->bf16 | degree histogram ----
__global__ void k_prep(const float* __restrict__ x, unsigned short* __restrict__ xb,
                       const float* __restrict__ W1, const float* __restrict__ W2,
                       unsigned short* __restrict__ W1t, unsigned short* __restrict__ W2t,
                       const int* __restrict__ ei, int* __restrict__ deg){
  const int b = blockIdx.x, t = threadIdx.x;
  if (b < PB_CONV){
    int base = (b * 256 + t) * 8;
    int row = base >> 9;
    u16x8 o;
    if (row < NN){
      const float4* p = (const float4*)(x + base);
      float4 a = p[0], c = p[1];
      o[0]=f2b(a.x); o[1]=f2b(a.y); o[2]=f2b(a.z); o[3]=f2b(a.w);
      o[4]=f2b(c.x); o[5]=f2b(c.y); o[6]=f2b(c.z); o[7]=f2b(c.w);
    } else {
      #pragma unroll
      for (int k=0;k<8;k++) o[k]=0;
    }
    *(u16x8*)(xb + base) = o;
  } else if (b < PB_CONV + PB_TRANS){
    int bb = b - PB_CONV;
    const float* W = (bb < 1024) ? W1 : W2;
    unsigned short* Wt = (bb < 1024) ? W1t : W2t;
    int idx = (bb & 1023) * 256 + t;
    int n = idx >> 9, k = idx & (CH - 1);
    Wt[n * CH + k] = f2b(W[k * CH + n]);
  } else {
    int e4 = ((b - PB_CONV - PB_TRANS) * 256 + t) * 4;
    if (e4 < NE){
      int4 d = *(const int4*)(ei + NE + e4);
      atomicAdd(&deg[d.x], 1); atomicAdd(&deg[d.y], 1);
      atomicAdd(&deg[d.z], 1); atomicAdd(&deg[d.w], 1);
    }
  }
}

// ---- hierarchical scan: block sums -> scan -> scatter ----
__global__ void k_blocksum(const int* __restrict__ deg, int* __restrict__ bsum){
  __shared__ int sh[4];
  const int t = threadIdx.x;
  int i = blockIdx.x * 256 + t;
  int v = (i < NN) ? deg[i] : 0;
  #pragma unroll
  for (int off = 32; off > 0; off >>= 1) v += __shfl_down(v, off, 64);
  if ((t & 63) == 0) sh[t >> 6] = v;
  __syncthreads();
  if (t == 0) bsum[blockIdx.x] = sh[0] + sh[1] + sh[2] + sh[3];
}

__global__ void k_scanoff(const int* __restrict__ bsum, int* __restrict__ boff,
                          int* __restrict__ row_ptr){
  __shared__ int sh[256];
  const int t = threadIdx.x;
  int v = (t < NB) ? bsum[t] : 0;
  sh[t] = v; __syncthreads();
  for (int d = 1; d < 256; d <<= 1){
    int add = (t >= d) ? sh[t - d] : 0;
    __syncthreads();
    sh[t] += add;
    __syncthreads();
  }
  if (t < NB) boff[t] = sh[t] - v;
  if (t == 255) row_ptr[NN] = sh[255];
}

__global__ void k_scatter(const int* __restrict__ deg, const int* __restrict__ boff,
                          int* __restrict__ row_ptr, int* __restrict__ cursor,
                          float* __restrict__ dinv){
  __shared__ int sh[256];
  const int t = threadIdx.x;
  int i = blockIdx.x * 256 + t;
  int d = (i < NN) ? deg[i] : 0;
  sh[t] = d; __syncthreads();
  for (int dd = 1; dd < 256; dd <<= 1){
    int add = (t >= dd) ? sh[t - dd] : 0;
    __syncthreads();
    sh[t] += add;
    __syncthreads();
  }
  if (i < NN){
    int ex = sh[t] - d + boff[blockIdx.x];
    row_ptr[i] = ex; cursor[i] = ex;
    dinv[i] = rsqrtf((float)d + 1.0f);   // +1 self-loop
  }
}

// ---- bucket edges by dst (2 edges/thread) ----
__global__ void k_bucket(const int* __restrict__ ei, int* __restrict__ cursor,
                         int* __restrict__ csr_src){
  int e2 = (blockIdx.x * blockDim.x + threadIdx.x) * 2;
  if (e2 >= NE) return;
  int2 src = *(const int2*)(ei + e2);
  int2 dst = *(const int2*)(ei + NE + e2);
  csr_src[atomicAdd(&cursor[dst.x], 1)] = src.x;
  csr_src[atomicAdd(&cursor[dst.y], 1)] = src.y;
}

// ---- bf16 MFMA GEMM: C[M,512] = A @ Bt^T, 128x256 tile, double-buffered LDS ----
// One barrier per K-iter: barrier drains vmcnt(0) => tile kb ready; then issue
// async stage of kb+1 into the alternate buffer while MFMAs consume kb.
__launch_bounds__(256, 2)
__global__ void k_gemm(const unsigned short* __restrict__ A,
                       const unsigned short* __restrict__ Bt,
                       unsigned short* __restrict__ C){
  __shared__ __align__(16) unsigned short As[2][128 * 32];   // 2 x 8 KB
  __shared__ __align__(16) unsigned short Bs[2][256 * 32];   // 2 x 16 KB
  const int t = threadIdx.x;
  const int wave = t >> 6, lane = t & 63;
  const int quad = lane >> 4, l15 = lane & 15;
  const int mw = (wave & 1) * 64;
  const int nw = (wave >> 1) * 128;
  const int rowBase = blockIdx.x * 128;
  const int nBase = blockIdx.y * 256;

  const int lr = lane >> 2;
  const int lc = (lane & 3) * 8;
  const unsigned short* Ag0 = A  + (size_t)(rowBase + wave * 32 + lr) * CH + lc;
  const unsigned short* Bg0 = Bt + (size_t)(nBase + wave * 64 + lr) * CH + lc;
  const int aoff = wave * 2 * 512;   // wave-uniform LDS chunk bases
  const int boff = wave * 4 * 512;

  f32x4 acc[4][8];
  #pragma unroll
  for (int i=0;i<4;i++)
    #pragma unroll
    for (int j=0;j<8;j++) acc[i][j] = 0;

  // prologue: stage tile 0 into buffer 0
  #pragma unroll
  for (int q=0;q<2;q++)
    __builtin_amdgcn_global_load_lds(
      (const __attribute__((address_space(1))) void*)(Ag0 + (size_t)q*16*CH),
      (__attribute__((address_space(3))) void*)(&As[0][aoff + q*512]), 16, 0, 0);
  #pragma unroll
  for (int q=0;q<4;q++)
    __builtin_amdgcn_global_load_lds(
      (const __attribute__((address_space(1))) void*)(Bg0 + (size_t)q*16*CH),
      (__attribute__((address_space(3))) void*)(&Bs[0][boff + q*512]), 16, 0, 0);

  for (int it = 0; it < 16; it++){
    const int cur = it & 1, nxt = cur ^ 1;
    __syncthreads();   // vmcnt(0)+barrier: buffer `cur` staged, `nxt` free
    if (it < 15){
      const int kb = (it + 1) * 32;
      #pragma unroll
      for (int q=0;q<2;q++)
        __builtin_amdgcn_global_load_lds(
          (const __attribute__((address_space(1))) void*)(Ag0 + (size_t)q*16*CH + kb),
          (__attribute__((address_space(3))) void*)(&As[nxt][aoff + q*512]), 16, 0, 0);
      #pragma unroll
      for (int q=0;q<4;q++)
        __builtin_amdgcn_global_load_lds(
          (const __attribute__((address_space(1))) void*)(Bg0 + (size_t)q*16*CH + kb),
          (__attribute__((address_space(3))) void*)(&Bs[nxt][boff + q*512]), 16, 0, 0);
    }
    bf16x8 af[4], bfr[8];
    #pragma unroll
    for (int i=0;i<4;i++)
      af[i] = __builtin_bit_cast(bf16x8,
              *(const u16x8*)&As[cur][(mw + i*16 + l15) * 32 + quad * 8]);
    #pragma unroll
    for (int j=0;j<8;j++)
      bfr[j] = __builtin_bit_cast(bf16x8,
              *(const u16x8*)&Bs[cur][(nw + j*16 + l15) * 32 + quad * 8]);
    #pragma unroll
    for (int i=0;i<4;i++)
      #pragma unroll
      for (int j=0;j<8;j++)
        acc[i][j] = __builtin_amdgcn_mfma_f32_16x16x32_bf16(af[i], bfr[j], acc[i][j], 0, 0, 0);
  }

  // C/D layout (m89-verified): col = lane&15, row = quad*4 + reg
  #pragma unroll
  for (int i=0;i<4;i++){
    #pragma unroll
    for (int j=0;j<8;j++){
      int r0 = rowBase + mw + i*16 + quad*4;
      int c  = nBase + nw + j*16 + l15;
      #pragma unroll
      for (int r=0;r<4;r++)
        C[(size_t)(r0 + r) * CH + c] = f2b(acc[i][j][r]);
    }
  }
}

// ---- aggregation (round-4 proven): relu(di*sum + di^2*self + b); optional head fuse ----
template<bool HEAD>
__launch_bounds__(256)
__global__ void k_agg(const unsigned short* __restrict__ h, const int* __restrict__ row_ptr,
                      const int* __restrict__ csr_src, const float* __restrict__ dinv,
                      const float* __restrict__ bias, unsigned short* __restrict__ out,
                      const float* __restrict__ Wo, const float* __restrict__ bo,
                      float* __restrict__ logits){
  const int node = blockIdx.x * 4 + (threadIdx.x >> 6);
  const int lane = threadIdx.x & 63;
  float acc[8];
  #pragma unroll
  for (int k=0;k<8;k++) acc[k] = 0.f;
  const int rp = row_ptr[node], re = row_ptr[node + 1];
  for (int base = rp; base < re; base += 64){
    int cnt = re - base; if (cnt > 64) cnt = 64;
    int s = 0; float w = 0.f;
    if (base + lane < re){ s = csr_src[base + lane]; w = dinv[s]; }
    int j = 0;
    for (; j + 8 <= cnt; j += 8){
      int ss[8]; float ww[8]; u16x8 hv[8];
      #pragma unroll
      for (int u=0;u<8;u++){
        ss[u] = __builtin_amdgcn_readlane(s, j + u);
        ww[u] = rdlane_f(w, j + u);
      }
      #pragma unroll
      for (int u=0;u<8;u++)
        hv[u] = *(const u16x8*)(h + (size_t)ss[u] * CH + lane * 8);
      #pragma unroll
      for (int u=0;u<8;u++)
        #pragma unroll
        for (int k=0;k<8;k++) acc[k] += ww[u] * b2f(hv[u][k]);
    }
    for (; j < cnt; j++){
      int ss = __builtin_amdgcn_readlane(s, j);
      float ww = rdlane_f(w, j);
      u16x8 hv = *(const u16x8*)(h + (size_t)ss * CH + lane * 8);
      #pragma unroll
      for (int k=0;k<8;k++) acc[k] += ww * b2f(hv[k]);
    }
  }
  const float di = dinv[node];
  u16x8 hs = *(const u16x8*)(h + (size_t)node * CH + lane * 8);
  const float4* bp = (const float4*)(bias + lane * 8);
  float4 bv0 = bp[0], bv1 = bp[1];
  float bb[8] = {bv0.x,bv0.y,bv0.z,bv0.w,bv1.x,bv1.y,bv1.z,bv1.w};
  if (HEAD){
    const float4* wp = (const float4*)(Wo + lane * 8);
    float4 w0 = wp[0], w1 = wp[1];
    float wv[8] = {w0.x,w0.y,w0.z,w0.w,w1.x,w1.y,w1.z,w1.w};
    float v = 0.f;
    #pragma unroll
    for (int k=0;k<8;k++){
      float r = fmaxf(di * acc[k] + di * di * b2f(hs[k]) + bb[k], 0.f);
      v += r * wv[k];
    }
    #pragma unroll
    for (int off = 32; off > 0; off >>= 1) v += __shfl_down(v, off, 64);
    if (lane == 0) logits[node] = v + bo[0];
  } else {
    u16x8 o;
    #pragma unroll
    for (int k=0;k<8;k++){
      float r = fmaxf(di * acc[k] + di * di * b2f(hs[k]) + bb[k], 0.f);
      o[k] = f2b(r);
    }
    *(u16x8*)(out + (size_t)node * CH + lane * 8) = o;
  }
}

// ---- softmax: 49-block partial (m_b, s_b) + 64-lane online combine ----
__global__ void k_smpart(const float* __restrict__ logits, float* __restrict__ pm,
                         float* __restrict__ ps){
  __shared__ float shm[16], shs[16];
  const int t = threadIdx.x;
  const int i = blockIdx.x * 1024 + t;
  float v = (i < NN) ? logits[i] : -3.4e38f;
  float m = v;
  #pragma unroll
  for (int off = 32; off > 0; off >>= 1) m = fmaxf(m, __shfl_down(m, off, 64));
  if ((t & 63) == 0) shm[t >> 6] = m;
  __syncthreads();
  if (t < 64){
    float mm = (t < 16) ? shm[t] : -3.4e38f;
    #pragma unroll
    for (int off = 8; off > 0; off >>= 1) mm = fmaxf(mm, __shfl_down(mm, off, 64));
    if (t == 0) shm[0] = mm;
  }
  __syncthreads();
  const float bm = shm[0];
  float s = (i < NN) ? expf(v - bm) : 0.f;
  #pragma unroll
  for (int off = 32; off > 0; off >>= 1) s += __shfl_down(s, off, 64);
  if ((t & 63) == 0) shs[t >> 6] = s;
  __syncthreads();
  if (t < 64){
    float sss = (t < 16) ? shs[t] : 0.f;
    #pragma unroll
    for (int off = 8; off > 0; off >>= 1) sss += __shfl_down(sss, off, 64);
    if (t == 0){ pm[blockIdx.x] = bm; ps[blockIdx.x] = sss; }
  }
}

__global__ void k_smfinal(const float* __restrict__ pm, const float* __restrict__ ps,
                          float* __restrict__ scr){
  const int t = threadIdx.x;   // 64 threads
  float m = (t < SMB) ? pm[t] : -3.4e38f;
  float M = m;
  #pragma unroll
  for (int off = 32; off > 0; off >>= 1) M = fmaxf(M, __shfl_down(M, off, 64));
  M = rdlane_f(M, 0);
  float s = (t < SMB) ? ps[t] * expf(m - M) : 0.f;
  #pragma unroll
  for (int off = 32; off > 0; off >>= 1) s += __shfl_down(s, off, 64);
  if (t == 0){ scr[0] = M; scr[1] = s; }
}

__global__ void k_smwrite(const float* __restrict__ logits, const float* __restrict__ scr,
                          float* __restrict__ out){
  int i = blockIdx.x * blockDim.x + threadIdx.x;
  if (i >= NN) return;
  out[i] = expf(logits[i] - scr[0]) / scr[1];
}

extern "C" void kernel_launch(void* const* d_in, const int* in_sizes, int n_in,
                              void* d_out, int out_size, void* d_ws, size_t ws_size,
                              hipStream_t stream){
  const float* x  = (const float*)d_in[0];
  const int*   ei = (const int*)d_in[1];
  const float* W1 = (const float*)d_in[2];
  const float* b1 = (const float*)d_in[3];
  const float* W2 = (const float*)d_in[4];
  const float* b2 = (const float*)d_in[5];
  const float* Wo = (const float*)d_in[6];
  const float* bo = (const float*)d_in[7];
  float* out = (float*)d_out;

  char* ws = (char*)d_ws;
  size_t off = 0;
  auto alloc = [&](size_t bytes) -> void* {
    void* p = ws + off;
    off = (off + bytes + 255) & ~(size_t)255;
    return p;
  };
  unsigned short* B0  = (unsigned short*)alloc((size_t)NP * CH * 2);
  unsigned short* B1  = (unsigned short*)alloc((size_t)NP * CH * 2);
  unsigned short* W1t = (unsigned short*)alloc((size_t)CH * CH * 2);
  unsigned short* W2t = (unsigned short*)alloc((size_t)CH * CH * 2);
  int*   deg     = (int*)alloc((size_t)NN * 4);
  float* dinv    = (float*)alloc((size_t)NN * 4);
  int*   row_ptr = (int*)alloc((size_t)(NN + 1) * 4);
  int*   cursor  = (int*)alloc((size_t)NN * 4);
  int*   csr     = (int*)alloc((size_t)NE * 4);
  float* logits  = (float*)alloc((size_t)NN * 4);
  int*   bsum    = (int*)alloc((size_t)NB * 4);
  int*   boff    = (int*)alloc((size_t)NB * 4);
  float* pm      = (float*)alloc((size_t)SMB * 4);
  float* ps      = (float*)alloc((size_t)SMB * 4);
  float* scr     = (float*)alloc(256);

  hipMemsetAsync(deg, 0, (size_t)NN * 4, stream);
  k_prep<<<PB_CONV + PB_TRANS + PB_DEG, 256, 0, stream>>>(x, B0, W1, W2, W1t, W2t, ei, deg);
  k_blocksum<<<NB, 256, 0, stream>>>(deg, bsum);
  k_scanoff<<<1, 256, 0, stream>>>(bsum, boff, row_ptr);
  k_scatter<<<NB, 256, 0, stream>>>(deg, boff, row_ptr, cursor, dinv);
  k_bucket<<<(NE / 2 + 255) / 256, 256, 0, stream>>>(ei, cursor, csr);

  k_gemm<<<dim3(NP / 128, CH / 256), 256, 0, stream>>>(B0, W1t, B1);
  k_agg<false><<<NN / 4, 256, 0, stream>>>(B1, row_ptr, csr, dinv, b1, B0,
                                           Wo, bo, logits);
  k_gemm<<<dim3(NP / 128, CH / 256), 256, 0, stream>>>(B0, W2t, B1);
  k_agg<true><<<NN / 4, 256, 0, stream>>>(B1, row_ptr, csr, dinv, b2, B0,
                                          Wo, bo, logits);

  k_smpart<<<SMB, 1024, 0, stream>>>(logits, pm, ps);
  k_smfinal<<<1, 64, 0, stream>>>(pm, ps, scr);
  k_smwrite<<<(NN + 255) / 256, 256, 0, stream>>>(logits, scr, out);
}

// Round 7
// 584.509 us; speedup vs baseline: 1.6538x; 1.0088x over previous
//
#include <hip/hip_runtime.h>

#define NN 50000
#define NP 50048
#define NE 800000
#define CH 512
#define NB 196        // ceil(50000/256) scan blocks
#define PB_CONV 12512 // NP*CH/8/256
#define PB_TRANS 2048 // 2 * CH*CH/256
#define PB_DEG 782    // ceil(NE/4/256)
#define PB_PERM 6     // 3*512/256 permuted-vector blocks
#define SMB 49        // softmax partial blocks (49*1024 >= 50000)

typedef __bf16 bf16x8 __attribute__((ext_vector_type(8)));
typedef float f32x4 __attribute__((ext_vector_type(4)));
typedef unsigned short u16x8 __attribute__((ext_vector_type(8)));

static __device__ __forceinline__ unsigned short f2b(float f){
  unsigned u = __builtin_bit_cast(unsigned, f);
  u = (u + 0x7fffu + ((u >> 16) & 1u)) >> 16;   // RNE f32 -> bf16
  return (unsigned short)u;
}
static __device__ __forceinline__ float b2f(unsigned short h){
  unsigned u = ((unsigned)h) << 16;
  return __builtin_bit_cast(float, u);
}
static __device__ __forceinline__ float rdlane_f(float v, int l){
  return __builtin_bit_cast(float, __builtin_amdgcn_readlane(__builtin_bit_cast(int, v), l));
}
// physical column p -> logical channel (epilogue permutation, within 128-blocks)
static __device__ __forceinline__ int lam(int p){
  return (p & ~127) | (((p & 7) << 4) + ((p & 127) >> 3));
}

// ---- merged prep: x->bf16 | W1t | W2t (k-permuted) | deg hist | permuted b1/b2/Wo ----
__global__ void k_prep(const float* __restrict__ x, unsigned short* __restrict__ xb,
                       const float* __restrict__ W1, const float* __restrict__ W2,
                       unsigned short* __restrict__ W1t, unsigned short* __restrict__ W2t,
                       const int* __restrict__ ei, int* __restrict__ deg,
                       const float* __restrict__ b1, const float* __restrict__ b2,
                       const float* __restrict__ Wo, float* __restrict__ b1p,
                       float* __restrict__ b2p, float* __restrict__ Wop){
  const int b = blockIdx.x, t = threadIdx.x;
  if (b < PB_CONV){
    int base = (b * 256 + t) * 8;
    int row = base >> 9;
    u16x8 o;
    if (row < NN){
      const float4* p = (const float4*)(x + base);
      float4 a = p[0], c = p[1];
      o[0]=f2b(a.x); o[1]=f2b(a.y); o[2]=f2b(a.z); o[3]=f2b(a.w);
      o[4]=f2b(c.x); o[5]=f2b(c.y); o[6]=f2b(c.z); o[7]=f2b(c.w);
    } else {
      #pragma unroll
      for (int k=0;k<8;k++) o[k]=0;
    }
    *(u16x8*)(xb + base) = o;
  } else if (b < PB_CONV + PB_TRANS){
    int bb = b - PB_CONV;
    int idx = (bb & 1023) * 256 + t;
    int n = idx >> 9, p = idx & (CH - 1);
    if (bb < 1024)
      W1t[n * CH + p] = f2b(W1[p * CH + n]);            // logical k
    else
      W2t[n * CH + p] = f2b(W2[lam(p) * CH + n]);       // k permuted to match B0 layout
  } else if (b < PB_CONV + PB_TRANS + PB_DEG){
    int e4 = ((b - PB_CONV - PB_TRANS) * 256 + t) * 4;
    if (e4 < NE){
      int4 d = *(const int4*)(ei + NE + e4);
      atomicAdd(&deg[d.x], 1); atomicAdd(&deg[d.y], 1);
      atomicAdd(&deg[d.z], 1); atomicAdd(&deg[d.w], 1);
    }
  } else {
    int idx = (b - PB_CONV - PB_TRANS - PB_DEG) * 256 + t;  // [0,1536)
    int which = idx >> 9, p = idx & (CH - 1);
    int l = lam(p);
    if (which == 0) b1p[p] = b1[l];
    else if (which == 1) b2p[p] = b2[l];
    else Wop[p] = Wo[l];
  }
}

// ---- hierarchical scan: block sums -> scan -> scatter ----
__global__ void k_blocksum(const int* __restrict__ deg, int* __restrict__ bsum){
  __shared__ int sh[4];
  const int t = threadIdx.x;
  int i = blockIdx.x * 256 + t;
  int v = (i < NN) ? deg[i] : 0;
  #pragma unroll
  for (int off = 32; off > 0; off >>= 1) v += __shfl_down(v, off, 64);
  if ((t & 63) == 0) sh[t >> 6] = v;
  __syncthreads();
  if (t == 0) bsum[blockIdx.x] = sh[0] + sh[1] + sh[2] + sh[3];
}

__global__ void k_scanoff(const int* __restrict__ bsum, int* __restrict__ boff,
                          int* __restrict__ row_ptr){
  __shared__ int sh[256];
  const int t = threadIdx.x;
  int v = (t < NB) ? bsum[t] : 0;
  sh[t] = v; __syncthreads();
  for (int d = 1; d < 256; d <<= 1){
    int add = (t >= d) ? sh[t - d] : 0;
    __syncthreads();
    sh[t] += add;
    __syncthreads();
  }
  if (t < NB) boff[t] = sh[t] - v;
  if (t == 255) row_ptr[NN] = sh[255];
}

__global__ void k_scatter(const int* __restrict__ deg, const int* __restrict__ boff,
                          int* __restrict__ row_ptr, int* __restrict__ cursor,
                          float* __restrict__ dinv){
  __shared__ int sh[256];
  const int t = threadIdx.x;
  int i = blockIdx.x * 256 + t;
  int d = (i < NN) ? deg[i] : 0;
  sh[t] = d; __syncthreads();
  for (int dd = 1; dd < 256; dd <<= 1){
    int add = (t >= dd) ? sh[t - dd] : 0;
    __syncthreads();
    sh[t] += add;
    __syncthreads();
  }
  if (i < NN){
    int ex = sh[t] - d + boff[blockIdx.x];
    row_ptr[i] = ex; cursor[i] = ex;
    dinv[i] = rsqrtf((float)d + 1.0f);   // +1 self-loop
  }
}

// ---- bucket edges by dst (2 edges/thread) ----
__global__ void k_bucket(const int* __restrict__ ei, int* __restrict__ cursor,
                         int* __restrict__ csr_src){
  int e2 = (blockIdx.x * blockDim.x + threadIdx.x) * 2;
  if (e2 >= NE) return;
  int2 src = *(const int2*)(ei + e2);
  int2 dst = *(const int2*)(ei + NE + e2);
  csr_src[atomicAdd(&cursor[dst.x], 1)] = src.x;
  csr_src[atomicAdd(&cursor[dst.y], 1)] = src.y;
}

// ---- bf16 MFMA GEMM: C[M,512] = A @ Bt^T, 128x256 tile, dbuf LDS ----
// Epilogue stores with intra-128-col permutation p = base + l15*8 + j:
// one dwordx4 (8 bf16) per (i,r) per lane — coalesced. Consumers use
// lam()-permuted vectors / k-permuted W2t so numerics are unchanged.
__launch_bounds__(256, 2)
__global__ void k_gemm(const unsigned short* __restrict__ A,
                       const unsigned short* __restrict__ Bt,
                       unsigned short* __restrict__ C){
  __shared__ __align__(16) unsigned short As[2][128 * 32];   // 2 x 8 KB
  __shared__ __align__(16) unsigned short Bs[2][256 * 32];   // 2 x 16 KB
  const int t = threadIdx.x;
  const int wave = t >> 6, lane = t & 63;
  const int quad = lane >> 4, l15 = lane & 15;
  const int mw = (wave & 1) * 64;
  const int nw = (wave >> 1) * 128;
  const int rowBase = blockIdx.x * 128;
  const int nBase = blockIdx.y * 256;

  const int lr = lane >> 2;
  const int lc = (lane & 3) * 8;
  const unsigned short* Ag0 = A  + (size_t)(rowBase + wave * 32 + lr) * CH + lc;
  const unsigned short* Bg0 = Bt + (size_t)(nBase + wave * 64 + lr) * CH + lc;
  const int aoff = wave * 2 * 512;
  const int boff = wave * 4 * 512;

  f32x4 acc[4][8];
  #pragma unroll
  for (int i=0;i<4;i++)
    #pragma unroll
    for (int j=0;j<8;j++) acc[i][j] = 0;

  #pragma unroll
  for (int q=0;q<2;q++)
    __builtin_amdgcn_global_load_lds(
      (const __attribute__((address_space(1))) void*)(Ag0 + (size_t)q*16*CH),
      (__attribute__((address_space(3))) void*)(&As[0][aoff + q*512]), 16, 0, 0);
  #pragma unroll
  for (int q=0;q<4;q++)
    __builtin_amdgcn_global_load_lds(
      (const __attribute__((address_space(1))) void*)(Bg0 + (size_t)q*16*CH),
      (__attribute__((address_space(3))) void*)(&Bs[0][boff + q*512]), 16, 0, 0);

  for (int it = 0; it < 16; it++){
    const int cur = it & 1, nxt = cur ^ 1;
    __syncthreads();
    if (it < 15){
      const int kb = (it + 1) * 32;
      #pragma unroll
      for (int q=0;q<2;q++)
        __builtin_amdgcn_global_load_lds(
          (const __attribute__((address_space(1))) void*)(Ag0 + (size_t)q*16*CH + kb),
          (__attribute__((address_space(3))) void*)(&As[nxt][aoff + q*512]), 16, 0, 0);
      #pragma unroll
      for (int q=0;q<4;q++)
        __builtin_amdgcn_global_load_lds(
          (const __attribute__((address_space(1))) void*)(Bg0 + (size_t)q*16*CH + kb),
          (__attribute__((address_space(3))) void*)(&Bs[nxt][boff + q*512]), 16, 0, 0);
    }
    bf16x8 af[4], bfr[8];
    #pragma unroll
    for (int i=0;i<4;i++)
      af[i] = __builtin_bit_cast(bf16x8,
              *(const u16x8*)&As[cur][(mw + i*16 + l15) * 32 + quad * 8]);
    #pragma unroll
    for (int j=0;j<8;j++)
      bfr[j] = __builtin_bit_cast(bf16x8,
              *(const u16x8*)&Bs[cur][(nw + j*16 + l15) * 32 + quad * 8]);
    #pragma unroll
    for (int i=0;i<4;i++)
      #pragma unroll
      for (int j=0;j<8;j++)
        acc[i][j] = __builtin_amdgcn_mfma_f32_16x16x32_bf16(af[i], bfr[j], acc[i][j], 0, 0, 0);
  }

  // permuted epilogue: lane packs its 8 j-values of one row -> 16B store
  #pragma unroll
  for (int i=0;i<4;i++){
    #pragma unroll
    for (int r=0;r<4;r++){
      int row = rowBase + mw + i*16 + quad*4 + r;
      u16x8 o;
      #pragma unroll
      for (int j=0;j<8;j++) o[j] = f2b(acc[i][j][r]);
      *(u16x8*)(C + (size_t)row * CH + nBase + nw + l15*8) = o;
    }
  }
}

// ---- aggregation: relu(di*sum + di^2*self + b); channels in physical (permuted) order ----
template<bool HEAD>
__launch_bounds__(256)
__global__ void k_agg(const unsigned short* __restrict__ h, const int* __restrict__ row_ptr,
                      const int* __restrict__ csr_src, const float* __restrict__ dinv,
                      const float* __restrict__ bias, unsigned short* __restrict__ out,
                      const float* __restrict__ Wo, const float* __restrict__ bo,
                      float* __restrict__ logits){
  const int node = blockIdx.x * 4 + (threadIdx.x >> 6);
  const int lane = threadIdx.x & 63;
  float acc[8];
  #pragma unroll
  for (int k=0;k<8;k++) acc[k] = 0.f;
  const int rp = row_ptr[node], re = row_ptr[node + 1];
  for (int base = rp; base < re; base += 64){
    int cnt = re - base; if (cnt > 64) cnt = 64;
    int s = 0; float w = 0.f;
    if (base + lane < re){ s = csr_src[base + lane]; w = dinv[s]; }
    int j = 0;
    for (; j + 8 <= cnt; j += 8){
      int ss[8]; float ww[8]; u16x8 hv[8];
      #pragma unroll
      for (int u=0;u<8;u++){
        ss[u] = __builtin_amdgcn_readlane(s, j + u);
        ww[u] = rdlane_f(w, j + u);
      }
      #pragma unroll
      for (int u=0;u<8;u++)
        hv[u] = *(const u16x8*)(h + (size_t)ss[u] * CH + lane * 8);
      #pragma unroll
      for (int u=0;u<8;u++)
        #pragma unroll
        for (int k=0;k<8;k++) acc[k] += ww[u] * b2f(hv[u][k]);
    }
    for (; j < cnt; j++){
      int ss = __builtin_amdgcn_readlane(s, j);
      float ww = rdlane_f(w, j);
      u16x8 hv = *(const u16x8*)(h + (size_t)ss * CH + lane * 8);
      #pragma unroll
      for (int k=0;k<8;k++) acc[k] += ww * b2f(hv[k]);
    }
  }
  const float di = dinv[node];
  u16x8 hs = *(const u16x8*)(h + (size_t)node * CH + lane * 8);
  const float4* bp = (const float4*)(bias + lane * 8);
  float4 bv0 = bp[0], bv1 = bp[1];
  float bb[8] = {bv0.x,bv0.y,bv0.z,bv0.w,bv1.x,bv1.y,bv1.z,bv1.w};
  if (HEAD){
    const float4* wp = (const float4*)(Wo + lane * 8);
    float4 w0 = wp[0], w1 = wp[1];
    float wv[8] = {w0.x,w0.y,w0.z,w0.w,w1.x,w1.y,w1.z,w1.w};
    float v = 0.f;
    #pragma unroll
    for (int k=0;k<8;k++){
      float r = fmaxf(di * acc[k] + di * di * b2f(hs[k]) + bb[k], 0.f);
      v += r * wv[k];
    }
    #pragma unroll
    for (int off = 32; off > 0; off >>= 1) v += __shfl_down(v, off, 64);
    if (lane == 0) logits[node] = v + bo[0];
  } else {
    u16x8 o;
    #pragma unroll
    for (int k=0;k<8;k++){
      float r = fmaxf(di * acc[k] + di * di * b2f(hs[k]) + bb[k], 0.f);
      o[k] = f2b(r);
    }
    *(u16x8*)(out + (size_t)node * CH + lane * 8) = o;
  }
}

// ---- softmax: 49-block partial (m_b, s_b); final combine folded into write ----
__global__ void k_smpart(const float* __restrict__ logits, float* __restrict__ pm,
                         float* __restrict__ ps){
  __shared__ float shm[16], shs[16];
  const int t = threadIdx.x;
  const int i = blockIdx.x * 1024 + t;
  float v = (i < NN) ? logits[i] : -3.4e38f;
  float m = v;
  #pragma unroll
  for (int off = 32; off > 0; off >>= 1) m = fmaxf(m, __shfl_down(m, off, 64));
  if ((t & 63) == 0) shm[t >> 6] = m;
  __syncthreads();
  if (t < 64){
    float mm = (t < 16) ? shm[t] : -3.4e38f;
    #pragma unroll
    for (int off = 8; off > 0; off >>= 1) mm = fmaxf(mm, __shfl_down(mm, off, 64));
    if (t == 0) shm[0] = mm;
  }
  __syncthreads();
  const float bm = shm[0];
  float s = (i < NN) ? expf(v - bm) : 0.f;
  #pragma unroll
  for (int off = 32; off > 0; off >>= 1) s += __shfl_down(s, off, 64);
  if ((t & 63) == 0) shs[t >> 6] = s;
  __syncthreads();
  if (t < 64){
    float sss = (t < 16) ? shs[t] : 0.f;
    #pragma unroll
    for (int off = 8; off > 0; off >>= 1) sss += __shfl_down(sss, off, 64);
    if (t == 0){ pm[blockIdx.x] = bm; ps[blockIdx.x] = sss; }
  }
}

__global__ void k_smwrite(const float* __restrict__ logits, const float* __restrict__ pm,
                          const float* __restrict__ ps, float* __restrict__ out){
  __shared__ float shMS[2];
  const int t = threadIdx.x;
  if (t < 64){
    float m = (t < SMB) ? pm[t] : -3.4e38f;
    float M = m;
    #pragma unroll
    for (int off = 32; off > 0; off >>= 1) M = fmaxf(M, __shfl_down(M, off, 64));
    M = rdlane_f(M, 0);
    float s = (t < SMB) ? ps[t] * expf(m - M) : 0.f;
    #pragma unroll
    for (int off = 32; off > 0; off >>= 1) s += __shfl_down(s, off, 64);
    if (t == 0){ shMS[0] = M; shMS[1] = s; }
  }
  __syncthreads();
  int i = blockIdx.x * blockDim.x + t;
  if (i < NN) out[i] = expf(logits[i] - shMS[0]) / shMS[1];
}

extern "C" void kernel_launch(void* const* d_in, const int* in_sizes, int n_in,
                              void* d_out, int out_size, void* d_ws, size_t ws_size,
                              hipStream_t stream){
  const float* x  = (const float*)d_in[0];
  const int*   ei = (const int*)d_in[1];
  const float* W1 = (const float*)d_in[2];
  const float* b1 = (const float*)d_in[3];
  const float* W2 = (const float*)d_in[4];
  const float* b2 = (const float*)d_in[5];
  const float* Wo = (const float*)d_in[6];
  const float* bo = (const float*)d_in[7];
  float* out = (float*)d_out;

  char* ws = (char*)d_ws;
  size_t off = 0;
  auto alloc = [&](size_t bytes) -> void* {
    void* p = ws + off;
    off = (off + bytes + 255) & ~(size_t)255;
    return p;
  };
  unsigned short* B0  = (unsigned short*)alloc((size_t)NP * CH * 2);
  unsigned short* B1  = (unsigned short*)alloc((size_t)NP * CH * 2);
  unsigned short* W1t = (unsigned short*)alloc((size_t)CH * CH * 2);
  unsigned short* W2t = (unsigned short*)alloc((size_t)CH * CH * 2);
  int*   deg     = (int*)alloc((size_t)NN * 4);
  float* dinv    = (float*)alloc((size_t)NN * 4);
  int*   row_ptr = (int*)alloc((size_t)(NN + 1) * 4);
  int*   cursor  = (int*)alloc((size_t)NN * 4);
  int*   csr     = (int*)alloc((size_t)NE * 4);
  float* logits  = (float*)alloc((size_t)NN * 4);
  int*   bsum    = (int*)alloc((size_t)NB * 4);
  int*   boff    = (int*)alloc((size_t)NB * 4);
  float* pm      = (float*)alloc((size_t)SMB * 4);
  float* ps      = (float*)alloc((size_t)SMB * 4);
  float* b1p     = (float*)alloc((size_t)CH * 4);
  float* b2p     = (float*)alloc((size_t)CH * 4);
  float* Wop     = (float*)alloc((size_t)CH * 4);

  hipMemsetAsync(deg, 0, (size_t)NN * 4, stream);
  k_prep<<<PB_CONV + PB_TRANS + PB_DEG + PB_PERM, 256, 0, stream>>>(
      x, B0, W1, W2, W1t, W2t, ei, deg, b1, b2, Wo, b1p, b2p, Wop);
  k_blocksum<<<NB, 256, 0, stream>>>(deg, bsum);
  k_scanoff<<<1, 256, 0, stream>>>(bsum, boff, row_ptr);
  k_scatter<<<NB, 256, 0, stream>>>(deg, boff, row_ptr, cursor, dinv);
  k_bucket<<<(NE / 2 + 255) / 256, 256, 0, stream>>>(ei, cursor, csr);

  k_gemm<<<dim3(NP / 128, CH / 256), 256, 0, stream>>>(B0, W1t, B1);
  k_agg<false><<<NN / 4, 256, 0, stream>>>(B1, row_ptr, csr, dinv, b1p, B0,
                                           Wop, bo, logits);
  k_gemm<<<dim3(NP / 128, CH / 256), 256, 0, stream>>>(B0, W2t, B1);
  k_agg<true><<<NN / 4, 256, 0, stream>>>(B1, row_ptr, csr, dinv, b2p, B0,
                                          Wop, bo, logits);

  k_smpart<<<SMB, 1024, 0, stream>>>(logits, pm, ps);
  k_smwrite<<<NB, 256, 0, stream>>>(logits, pm, ps, out);
}

// Round 8
// 563.709 us; speedup vs baseline: 1.7149x; 1.0369x over previous
//
#include <hip/hip_runtime.h>

#define NN 50000
#define NP 50048
#define NE 800000
#define CH 512
#define NB 196        // ceil(50000/256) scan blocks
#define PB_CONV 12512 // NP*CH/8/256
#define PB_TRANS 2048 // 2 * CH*CH/256
#define PB_DEG 782    // ceil(NE/4/256)
#define PB_PERM 6     // 3*512/256 permuted-vector blocks
#define SMB 49        // softmax partial blocks (49*1024 >= 50000)

typedef __bf16 bf16x8 __attribute__((ext_vector_type(8)));
typedef float f32x4 __attribute__((ext_vector_type(4)));
typedef unsigned short u16x8 __attribute__((ext_vector_type(8)));

static __device__ __forceinline__ unsigned short f2b(float f){
  unsigned u = __builtin_bit_cast(unsigned, f);
  u = (u + 0x7fffu + ((u >> 16) & 1u)) >> 16;   // RNE f32 -> bf16
  return (unsigned short)u;
}
static __device__ __forceinline__ float b2f(unsigned short h){
  unsigned u = ((unsigned)h) << 16;
  return __builtin_bit_cast(float, u);
}
static __device__ __forceinline__ float rdlane_f(float v, int l){
  return __builtin_bit_cast(float, __builtin_amdgcn_readlane(__builtin_bit_cast(int, v), l));
}
// physical column p -> logical channel (epilogue permutation, within 128-blocks)
static __device__ __forceinline__ int lam(int p){
  return (p & ~127) | (((p & 7) << 4) + ((p & 127) >> 3));
}

// ---- merged prep: x->bf16 | W1t | W2t (k-permuted) | deg hist (+edge rank) | permuted vecs ----
__global__ void k_prep(const float* __restrict__ x, unsigned short* __restrict__ xb,
                       const float* __restrict__ W1, const float* __restrict__ W2,
                       unsigned short* __restrict__ W1t, unsigned short* __restrict__ W2t,
                       const int* __restrict__ ei, int* __restrict__ deg,
                       int* __restrict__ rank,
                       const float* __restrict__ b1, const float* __restrict__ b2,
                       const float* __restrict__ Wo, float* __restrict__ b1p,
                       float* __restrict__ b2p, float* __restrict__ Wop){
  const int b = blockIdx.x, t = threadIdx.x;
  if (b < PB_CONV){
    int base = (b * 256 + t) * 8;
    int row = base >> 9;
    u16x8 o;
    if (row < NN){
      const float4* p = (const float4*)(x + base);
      float4 a = p[0], c = p[1];
      o[0]=f2b(a.x); o[1]=f2b(a.y); o[2]=f2b(a.z); o[3]=f2b(a.w);
      o[4]=f2b(c.x); o[5]=f2b(c.y); o[6]=f2b(c.z); o[7]=f2b(c.w);
    } else {
      #pragma unroll
      for (int k=0;k<8;k++) o[k]=0;
    }
    *(u16x8*)(xb + base) = o;
  } else if (b < PB_CONV + PB_TRANS){
    int bb = b - PB_CONV;
    int idx = (bb & 1023) * 256 + t;
    int n = idx >> 9, p = idx & (CH - 1);
    if (bb < 1024)
      W1t[n * CH + p] = f2b(W1[p * CH + n]);            // logical k
    else
      W2t[n * CH + p] = f2b(W2[lam(p) * CH + n]);       // k permuted to match B0 layout
  } else if (b < PB_CONV + PB_TRANS + PB_DEG){
    int e4 = ((b - PB_CONV - PB_TRANS) * 256 + t) * 4;
    if (e4 < NE){
      int4 d = *(const int4*)(ei + NE + e4);
      int4 r;
      r.x = atomicAdd(&deg[d.x], 1);
      r.y = atomicAdd(&deg[d.y], 1);
      r.z = atomicAdd(&deg[d.z], 1);
      r.w = atomicAdd(&deg[d.w], 1);
      *(int4*)(rank + e4) = r;   // within-node rank; makes bucket atomic-free
    }
  } else {
    int idx = (b - PB_CONV - PB_TRANS - PB_DEG) * 256 + t;  // [0,1536)
    int which = idx >> 9, p = idx & (CH - 1);
    int l = lam(p);
    if (which == 0) b1p[p] = b1[l];
    else if (which == 1) b2p[p] = b2[l];
    else Wop[p] = Wo[l];
  }
}

// ---- hierarchical scan: block sums -> scan -> scatter ----
__global__ void k_blocksum(const int* __restrict__ deg, int* __restrict__ bsum){
  __shared__ int sh[4];
  const int t = threadIdx.x;
  int i = blockIdx.x * 256 + t;
  int v = (i < NN) ? deg[i] : 0;
  #pragma unroll
  for (int off = 32; off > 0; off >>= 1) v += __shfl_down(v, off, 64);
  if ((t & 63) == 0) sh[t >> 6] = v;
  __syncthreads();
  if (t == 0) bsum[blockIdx.x] = sh[0] + sh[1] + sh[2] + sh[3];
}

__global__ void k_scanoff(const int* __restrict__ bsum, int* __restrict__ boff,
                          int* __restrict__ row_ptr){
  __shared__ int sh[256];
  const int t = threadIdx.x;
  int v = (t < NB) ? bsum[t] : 0;
  sh[t] = v; __syncthreads();
  for (int d = 1; d < 256; d <<= 1){
    int add = (t >= d) ? sh[t - d] : 0;
    __syncthreads();
    sh[t] += add;
    __syncthreads();
  }
  if (t < NB) boff[t] = sh[t] - v;
  if (t == 255) row_ptr[NN] = sh[255];
}

__global__ void k_scatter(const int* __restrict__ deg, const int* __restrict__ boff,
                          int* __restrict__ row_ptr, float* __restrict__ dinv){
  __shared__ int sh[256];
  const int t = threadIdx.x;
  int i = blockIdx.x * 256 + t;
  int d = (i < NN) ? deg[i] : 0;
  sh[t] = d; __syncthreads();
  for (int dd = 1; dd < 256; dd <<= 1){
    int add = (t >= dd) ? sh[t - dd] : 0;
    __syncthreads();
    sh[t] += add;
    __syncthreads();
  }
  if (i < NN){
    row_ptr[i] = sh[t] - d + boff[blockIdx.x];
    dinv[i] = rsqrtf((float)d + 1.0f);   // +1 self-loop
  }
}

// ---- bucket edges by dst: atomic-free (rank precomputed in k_prep) ----
__global__ void k_bucket(const int* __restrict__ ei, const int* __restrict__ row_ptr,
                         const int* __restrict__ rank, int* __restrict__ csr_src){
  int e2 = (blockIdx.x * blockDim.x + threadIdx.x) * 2;
  if (e2 >= NE) return;
  int2 src = *(const int2*)(ei + e2);
  int2 dst = *(const int2*)(ei + NE + e2);
  int2 rk  = *(const int2*)(rank + e2);
  csr_src[row_ptr[dst.x] + rk.x] = src.x;
  csr_src[row_ptr[dst.y] + rk.y] = src.y;
}

// ---- bf16 MFMA GEMM: C[M,512] = A @ Bt^T, 128x256 tile, dbuf LDS ----
// 1-D grid, pair-swizzled: blocks 2k/2k+1 share A rows (L2 A reuse).
// Permuted epilogue: p = base + l15*8 + j -> one 16B store per (i,r).
__launch_bounds__(256, 2)
__global__ void k_gemm(const unsigned short* __restrict__ A,
                       const unsigned short* __restrict__ Bt,
                       unsigned short* __restrict__ C){
  __shared__ __align__(16) unsigned short As[2][128 * 32];   // 2 x 8 KB
  __shared__ __align__(16) unsigned short Bs[2][256 * 32];   // 2 x 16 KB
  const int t = threadIdx.x;
  const int wave = t >> 6, lane = t & 63;
  const int quad = lane >> 4, l15 = lane & 15;
  const int mw = (wave & 1) * 64;
  const int nw = (wave >> 1) * 128;
  const int rowBase = (blockIdx.x >> 1) * 128;
  const int nBase = (blockIdx.x & 1) * 256;

  const int lr = lane >> 2;
  const int lc = (lane & 3) * 8;
  const unsigned short* Ag0 = A  + (size_t)(rowBase + wave * 32 + lr) * CH + lc;
  const unsigned short* Bg0 = Bt + (size_t)(nBase + wave * 64 + lr) * CH + lc;
  const int aoff = wave * 2 * 512;
  const int boff = wave * 4 * 512;

  f32x4 acc[4][8];
  #pragma unroll
  for (int i=0;i<4;i++)
    #pragma unroll
    for (int j=0;j<8;j++) acc[i][j] = 0;

  #pragma unroll
  for (int q=0;q<2;q++)
    __builtin_amdgcn_global_load_lds(
      (const __attribute__((address_space(1))) void*)(Ag0 + (size_t)q*16*CH),
      (__attribute__((address_space(3))) void*)(&As[0][aoff + q*512]), 16, 0, 0);
  #pragma unroll
  for (int q=0;q<4;q++)
    __builtin_amdgcn_global_load_lds(
      (const __attribute__((address_space(1))) void*)(Bg0 + (size_t)q*16*CH),
      (__attribute__((address_space(3))) void*)(&Bs[0][boff + q*512]), 16, 0, 0);

  for (int it = 0; it < 16; it++){
    const int cur = it & 1, nxt = cur ^ 1;
    __syncthreads();
    if (it < 15){
      const int kb = (it + 1) * 32;
      #pragma unroll
      for (int q=0;q<2;q++)
        __builtin_amdgcn_global_load_lds(
          (const __attribute__((address_space(1))) void*)(Ag0 + (size_t)q*16*CH + kb),
          (__attribute__((address_space(3))) void*)(&As[nxt][aoff + q*512]), 16, 0, 0);
      #pragma unroll
      for (int q=0;q<4;q++)
        __builtin_amdgcn_global_load_lds(
          (const __attribute__((address_space(1))) void*)(Bg0 + (size_t)q*16*CH + kb),
          (__attribute__((address_space(3))) void*)(&Bs[nxt][boff + q*512]), 16, 0, 0);
    }
    bf16x8 af[4], bfr[8];
    #pragma unroll
    for (int i=0;i<4;i++)
      af[i] = __builtin_bit_cast(bf16x8,
              *(const u16x8*)&As[cur][(mw + i*16 + l15) * 32 + quad * 8]);
    #pragma unroll
    for (int j=0;j<8;j++)
      bfr[j] = __builtin_bit_cast(bf16x8,
              *(const u16x8*)&Bs[cur][(nw + j*16 + l15) * 32 + quad * 8]);
    #pragma unroll
    for (int i=0;i<4;i++)
      #pragma unroll
      for (int j=0;j<8;j++)
        acc[i][j] = __builtin_amdgcn_mfma_f32_16x16x32_bf16(af[i], bfr[j], acc[i][j], 0, 0, 0);
  }

  #pragma unroll
  for (int i=0;i<4;i++){
    #pragma unroll
    for (int r=0;r<4;r++){
      int row = rowBase + mw + i*16 + quad*4 + r;
      u16x8 o;
      #pragma unroll
      for (int j=0;j<8;j++) o[j] = f2b(acc[i][j][r]);
      *(u16x8*)(C + (size_t)row * CH + nBase + nw + l15*8) = o;
    }
  }
}

// ---- aggregation: relu(di*sum + di^2*self + b); split into node ranges for visibility ----
template<bool HEAD>
__launch_bounds__(256)
__global__ void k_agg(const unsigned short* __restrict__ h, const int* __restrict__ row_ptr,
                      const int* __restrict__ csr_src, const float* __restrict__ dinv,
                      const float* __restrict__ bias, unsigned short* __restrict__ out,
                      const float* __restrict__ Wo, const float* __restrict__ bo,
                      float* __restrict__ logits, int nodeBase){
  const int node = nodeBase + blockIdx.x * 4 + (threadIdx.x >> 6);
  const int lane = threadIdx.x & 63;
  float acc[8];
  #pragma unroll
  for (int k=0;k<8;k++) acc[k] = 0.f;
  const int rp = row_ptr[node], re = row_ptr[node + 1];
  for (int base = rp; base < re; base += 64){
    int cnt = re - base; if (cnt > 64) cnt = 64;
    int s = 0; float w = 0.f;
    if (base + lane < re){ s = csr_src[base + lane]; w = dinv[s]; }
    int j = 0;
    for (; j + 8 <= cnt; j += 8){
      int ss[8]; float ww[8]; u16x8 hv[8];
      #pragma unroll
      for (int u=0;u<8;u++){
        ss[u] = __builtin_amdgcn_readlane(s, j + u);
        ww[u] = rdlane_f(w, j + u);
      }
      #pragma unroll
      for (int u=0;u<8;u++)
        hv[u] = *(const u16x8*)(h + (size_t)ss[u] * CH + lane * 8);
      #pragma unroll
      for (int u=0;u<8;u++)
        #pragma unroll
        for (int k=0;k<8;k++) acc[k] += ww[u] * b2f(hv[u][k]);
    }
    for (; j < cnt; j++){
      int ss = __builtin_amdgcn_readlane(s, j);
      float ww = rdlane_f(w, j);
      u16x8 hv = *(const u16x8*)(h + (size_t)ss * CH + lane * 8);
      #pragma unroll
      for (int k=0;k<8;k++) acc[k] += ww * b2f(hv[k]);
    }
  }
  const float di = dinv[node];
  u16x8 hs = *(const u16x8*)(h + (size_t)node * CH + lane * 8);
  const float4* bp = (const float4*)(bias + lane * 8);
  float4 bv0 = bp[0], bv1 = bp[1];
  float bb[8] = {bv0.x,bv0.y,bv0.z,bv0.w,bv1.x,bv1.y,bv1.z,bv1.w};
  if (HEAD){
    const float4* wp = (const float4*)(Wo + lane * 8);
    float4 w0 = wp[0], w1 = wp[1];
    float wv[8] = {w0.x,w0.y,w0.z,w0.w,w1.x,w1.y,w1.z,w1.w};
    float v = 0.f;
    #pragma unroll
    for (int k=0;k<8;k++){
      float r = fmaxf(di * acc[k] + di * di * b2f(hs[k]) + bb[k], 0.f);
      v += r * wv[k];
    }
    #pragma unroll
    for (int off = 32; off > 0; off >>= 1) v += __shfl_down(v, off, 64);
    if (lane == 0) logits[node] = v + bo[0];
  } else {
    u16x8 o;
    #pragma unroll
    for (int k=0;k<8;k++){
      float r = fmaxf(di * acc[k] + di * di * b2f(hs[k]) + bb[k], 0.f);
      o[k] = f2b(r);
    }
    *(u16x8*)(out + (size_t)node * CH + lane * 8) = o;
  }
}

// ---- softmax: 49-block partial (m_b, s_b); final combine folded into write ----
__global__ void k_smpart(const float* __restrict__ logits, float* __restrict__ pm,
                         float* __restrict__ ps){
  __shared__ float shm[16], shs[16];
  const int t = threadIdx.x;
  const int i = blockIdx.x * 1024 + t;
  float v = (i < NN) ? logits[i] : -3.4e38f;
  float m = v;
  #pragma unroll
  for (int off = 32; off > 0; off >>= 1) m = fmaxf(m, __shfl_down(m, off, 64));
  if ((t & 63) == 0) shm[t >> 6] = m;
  __syncthreads();
  if (t < 64){
    float mm = (t < 16) ? shm[t] : -3.4e38f;
    #pragma unroll
    for (int off = 8; off > 0; off >>= 1) mm = fmaxf(mm, __shfl_down(mm, off, 64));
    if (t == 0) shm[0] = mm;
  }
  __syncthreads();
  const float bm = shm[0];
  float s = (i < NN) ? expf(v - bm) : 0.f;
  #pragma unroll
  for (int off = 32; off > 0; off >>= 1) s += __shfl_down(s, off, 64);
  if ((t & 63) == 0) shs[t >> 6] = s;
  __syncthreads();
  if (t < 64){
    float sss = (t < 16) ? shs[t] : 0.f;
    #pragma unroll
    for (int off = 8; off > 0; off >>= 1) sss += __shfl_down(sss, off, 64);
    if (t == 0){ pm[blockIdx.x] = bm; ps[blockIdx.x] = sss; }
  }
}

__global__ void k_smwrite(const float* __restrict__ logits, const float* __restrict__ pm,
                          const float* __restrict__ ps, float* __restrict__ out){
  __shared__ float shMS[2];
  const int t = threadIdx.x;
  if (t < 64){
    float m = (t < SMB) ? pm[t] : -3.4e38f;
    float M = m;
    #pragma unroll
    for (int off = 32; off > 0; off >>= 1) M = fmaxf(M, __shfl_down(M, off, 64));
    M = rdlane_f(M, 0);
    float s = (t < SMB) ? ps[t] * expf(m - M) : 0.f;
    #pragma unroll
    for (int off = 32; off > 0; off >>= 1) s += __shfl_down(s, off, 64);
    if (t == 0){ shMS[0] = M; shMS[1] = s; }
  }
  __syncthreads();
  int i = blockIdx.x * blockDim.x + t;
  if (i < NN) out[i] = expf(logits[i] - shMS[0]) / shMS[1];
}

extern "C" void kernel_launch(void* const* d_in, const int* in_sizes, int n_in,
                              void* d_out, int out_size, void* d_ws, size_t ws_size,
                              hipStream_t stream){
  const float* x  = (const float*)d_in[0];
  const int*   ei = (const int*)d_in[1];
  const float* W1 = (const float*)d_in[2];
  const float* b1 = (const float*)d_in[3];
  const float* W2 = (const float*)d_in[4];
  const float* b2 = (const float*)d_in[5];
  const float* Wo = (const float*)d_in[6];
  const float* bo = (const float*)d_in[7];
  float* out = (float*)d_out;

  char* ws = (char*)d_ws;
  size_t off = 0;
  auto alloc = [&](size_t bytes) -> void* {
    void* p = ws + off;
    off = (off + bytes + 255) & ~(size_t)255;
    return p;
  };
  unsigned short* B0  = (unsigned short*)alloc((size_t)NP * CH * 2);
  unsigned short* B1  = (unsigned short*)alloc((size_t)NP * CH * 2);
  unsigned short* W1t = (unsigned short*)alloc((size_t)CH * CH * 2);
  unsigned short* W2t = (unsigned short*)alloc((size_t)CH * CH * 2);
  int*   deg     = (int*)alloc((size_t)NN * 4);
  float* dinv    = (float*)alloc((size_t)NN * 4);
  int*   row_ptr = (int*)alloc((size_t)(NN + 1) * 4);
  int*   rank    = (int*)alloc((size_t)NE * 4);
  int*   csr     = (int*)alloc((size_t)NE * 4);
  float* logits  = (float*)alloc((size_t)NN * 4);
  int*   bsum    = (int*)alloc((size_t)NB * 4);
  int*   boff    = (int*)alloc((size_t)NB * 4);
  float* pm      = (float*)alloc((size_t)SMB * 4);
  float* ps      = (float*)alloc((size_t)SMB * 4);
  float* b1p     = (float*)alloc((size_t)CH * 4);
  float* b2p     = (float*)alloc((size_t)CH * 4);
  float* Wop     = (float*)alloc((size_t)CH * 4);

  hipMemsetAsync(deg, 0, (size_t)NN * 4, stream);
  k_prep<<<PB_CONV + PB_TRANS + PB_DEG + PB_PERM, 256, 0, stream>>>(
      x, B0, W1, W2, W1t, W2t, ei, deg, rank, b1, b2, Wo, b1p, b2p, Wop);
  k_blocksum<<<NB, 256, 0, stream>>>(deg, bsum);
  k_scanoff<<<1, 256, 0, stream>>>(bsum, boff, row_ptr);
  k_scatter<<<NB, 256, 0, stream>>>(deg, boff, row_ptr, dinv);
  k_bucket<<<(NE / 2 + 255) / 256, 256, 0, stream>>>(ei, row_ptr, rank, csr);

  k_gemm<<<2 * (NP / 128), 256, 0, stream>>>(B0, W1t, B1);
  k_agg<false><<<NN / 8, 256, 0, stream>>>(B1, row_ptr, csr, dinv, b1p, B0,
                                           Wop, bo, logits, 0);
  k_agg<false><<<NN / 8, 256, 0, stream>>>(B1, row_ptr, csr, dinv, b1p, B0,
                                           Wop, bo, logits, NN / 2);
  k_gemm<<<2 * (NP / 128), 256, 0, stream>>>(B0, W2t, B1);
  k_agg<true><<<NN / 8, 256, 0, stream>>>(B1, row_ptr, csr, dinv, b2p, B0,
                                          Wop, bo, logits, 0);
  k_agg<true><<<NN / 8, 256, 0, stream>>>(B1, row_ptr, csr, dinv, b2p, B0,
                                          Wop, bo, logits, NN / 2);

  k_smpart<<<SMB, 1024, 0, stream>>>(logits, pm, ps);
  k_smwrite<<<NB, 256, 0, stream>>>(logits, pm, ps, out);
}